// Round 2
// baseline (920.938 us; speedup 1.0000x reference)
//
#include <hip/hip_runtime.h>
#include <hip/hip_bf16.h>

// Problem constants (from reference setup_inputs: t1_t0=1, TOL=0.05 -> 20 steps)
#define MB   32      // batch
#define NCH  4       // state channels
#define LL   2048    // spatial length
#define HID  64      // hidden channels
#define KSZ  5       // conv kernel size
#define GG   10      // ghost cells (IGST)
#define RI   (LL - 2*GG)   // 2028 interior length
#define TPOS 128     // positions per block tile
#define NTILES 16    // ceil(2028/128)
#define THR  256
#define NSTEPS 20

__device__ __forceinline__ int pmap(int q) {
  // bdry read map: ghost -> interior source (period RI)
  if (q < GG) return q + RI;
  if (q >= LL - GG) return q - RI;
  return q;
}

template<bool MAP, bool SCATTER>
__global__ __launch_bounds__(THR, 2)
void stage_kernel(const float* __restrict__ z,
                  const float* __restrict__ cin,
                  float* __restrict__ outp,
                  const float* __restrict__ W1g, const float* __restrict__ b1g,
                  const float* __restrict__ W2g, const float* __restrict__ b2g,
                  float ca, float cb, float cc_)
{
  // out[p] = ca*z[p] + cb*cin[p] + cc_*f(cin~)[p] for interior p; optional ghost scatter.
  // cin~ = raw cin (stage 1) or bdry(cin) via pmap (stages 2,3).
  __shared__ float in_s[NCH][TPOS + 8];                    // conv input tile (+/-4 halo)
  __shared__ __align__(16) float th_s[TPOS + 4][HID];      // tanh(conv1) tile, chunk-swizzled
  __shared__ __align__(16) float w2s[NCH][KSZ][HID];       // W2 transposed [co][k][c]
  __shared__ float b2s[NCH];

  const int t    = threadIdx.x;
  const int tile = blockIdx.x;
  const int mi   = blockIdx.y;
  const int p0   = GG + tile * TPOS;
  const int validT = min(TPOS, (LL - GG) - p0);            // 128, last tile 108

  const float* zb   = z   + mi * (NCH * LL);
  const float* cinb = cin + mi * (NCH * LL);
  float*       outb = outp + mi * (NCH * LL);

  // ---- load conv-input tile (through map for stages 2/3; raw for stage 1) ----
  const int LOADN = validT + 8;
  for (int i = t; i < NCH * (TPOS + 8); i += THR) {
    int ci = i / (TPOS + 8);
    int j  = i - ci * (TPOS + 8);
    if (j < LOADN) {
      int q  = p0 - 4 + j;
      int qq = MAP ? pmap(q) : q;      // raw q always in [6, 2042) -> in bounds
      in_s[ci][j] = cinb[ci * LL + qq];
    }
  }
  // ---- load W2 transposed + b2 into LDS ----
  for (int i = t; i < NCH * KSZ * HID; i += THR) {
    int co  = i / (KSZ * HID);
    int rem = i - co * (KSZ * HID);
    int k   = rem / HID;
    int c2  = rem - k * HID;
    w2s[co][k][c2] = W2g[(co * HID + c2) * KSZ + k];
  }
  if (t < NCH) b2s[t] = b2g[t];

  // ---- per-thread conv1 weights (thread <-> hidden channel) ----
  const int c  = t & 63;
  const int pg = t >> 6;
  float w1r[NCH * KSZ];
  #pragma unroll
  for (int i = 0; i < NCH * KSZ; ++i) w1r[i] = W1g[c * (NCH * KSZ) + i];
  const float b1r = b1g[c];

  __syncthreads();

  // ---- phase 1: hidden = tanh(conv1(input)), rows [0, validT+4) ----
  {
    const int THN = validT + 4;
    const int j0  = pg * 35;                 // multiple of 5 -> static rotation
    const int j1  = min(THN, j0 + 35);
    float zw[NCH][KSZ];
    #pragma unroll
    for (int d = 0; d < 4; ++d) {
      #pragma unroll
      for (int ci = 0; ci < NCH; ++ci)
        zw[ci][d] = in_s[ci][j0 + d];        // slot (j0+d)%5 == d
    }
    for (int jb = j0; jb < j1; jb += 5) {
      #pragma unroll
      for (int u = 0; u < 5; ++u) {
        int j = jb + u;
        if (j < j1) {
          #pragma unroll
          for (int ci = 0; ci < NCH; ++ci)
            zw[ci][(u + 4) % 5] = in_s[ci][j + 4];
          float acc = b1r;
          #pragma unroll
          for (int ci = 0; ci < NCH; ++ci) {
            #pragma unroll
            for (int k = 0; k < KSZ; ++k)
              acc = fmaf(w1r[ci * KSZ + k], zw[ci][(u + k) % 5], acc);
          }
          // fast tanh: 1 - 2/(e^{2x}+1)
          float e  = __expf(2.0f * acc);
          float th = 1.0f - 2.0f * __frcp_rn(e + 1.0f);
          // chunk-XOR swizzle: chunk (c>>2) stored at slot (c>>2)^(j&15)
          th_s[j][(((c >> 2) ^ (j & 15)) << 2) | (c & 3)] = th;
        }
      }
    }
  }

  __syncthreads();

  // ---- phase 2: conv2 + combine + write (+ ghost scatter for carry) ----
  // Lane mapping x = t>>1: lane pairs share rows (LDS broadcast), halving
  // the distinct-address fan-in per bank group (8-way -> ~4-way conflicts).
  {
    const int x   = t >> 1;           // position within tile
    const int cop = t & 1;            // 0 -> co {0,1}, 1 -> co {2,3}
    if (x < validT) {
      const int co0 = cop * 2, co1 = co0 + 1;
      float a0 = b2s[co0], a1 = b2s[co1];
      const float4* w2v0 = (const float4*)&w2s[co0][0][0];
      const float4* w2v1 = (const float4*)&w2s[co1][0][0];
      #pragma unroll
      for (int k = 0; k < KSZ; ++k) {
        const int row = x + k;
        const float4* thv = (const float4*)&th_s[row][0];
        const int rs = row & 15;
        #pragma unroll
        for (int ccn = 0; ccn < 16; ++ccn) {
          float4 tv = thv[ccn ^ rs];
          float4 wa = w2v0[k * 16 + ccn];
          float4 wb = w2v1[k * 16 + ccn];
          a0 = fmaf(tv.x, wa.x, a0); a0 = fmaf(tv.y, wa.y, a0);
          a0 = fmaf(tv.z, wa.z, a0); a0 = fmaf(tv.w, wa.w, a0);
          a1 = fmaf(tv.x, wb.x, a1); a1 = fmaf(tv.y, wb.y, a1);
          a1 = fmaf(tv.z, wb.z, a1); a1 = fmaf(tv.w, wb.w, a1);
        }
      }
      const int p = p0 + x;
      float v0 = ca * zb[co0 * LL + p] + cb * cinb[co0 * LL + p] + cc_ * a0;
      float v1 = ca * zb[co1 * LL + p] + cb * cinb[co1 * LL + p] + cc_ * a1;
      outb[co0 * LL + p] = v0;
      outb[co1 * LL + p] = v1;
      if (SCATTER) {
        if (p >= LL - 2 * GG && p < LL - GG) {   // -> low ghosts [0,G)
          outb[co0 * LL + p - RI] = v0;
          outb[co1 * LL + p - RI] = v1;
        }
        if (p >= GG && p < 2 * GG) {             // -> high ghosts [L-G,L)
          outb[co0 * LL + p + RI] = v0;
          outb[co1 * LL + p + RI] = v1;
        }
      }
    }
  }
}

extern "C" void kernel_launch(void* const* d_in, const int* in_sizes, int n_in,
                              void* d_out, int out_size, void* d_ws, size_t ws_size,
                              hipStream_t stream) {
  const float* z0 = (const float*)d_in[0];
  const float* W1 = (const float*)d_in[1];
  const float* b1 = (const float*)d_in[2];
  const float* W2 = (const float*)d_in[3];
  const float* b2 = (const float*)d_in[4];
  float* out = (float*)d_out;

  const size_t ELEMS = (size_t)MB * NCH * LL;  // 262144 floats = 1 MiB
  float* zA  = (float*)d_ws;
  float* zB  = zA + ELEMS;
  float* u1p = zB + ELEMS;
  float* u2p = u1p + ELEMS;

  const float h = 0.05f;  // t1_t0 / n_steps = 1/20
  dim3 grid(NTILES, MB);
  dim3 block(THR);

  const float* zc = z0;
  for (int s = 0; s < NSTEPS; ++s) {
    float* znext = (s == NSTEPS - 1) ? out : ((s & 1) ? zB : zA);
    // stage 1: u1 = z + h*f(z)            (raw reads, incl. raw ghosts of z)
    stage_kernel<false, false><<<grid, block, 0, stream>>>(
        zc, zc, u1p, W1, b1, W2, b2, 1.0f, 0.0f, h);
    // stage 2: u2 = 0.75 z + 0.25 bdry(u1) + 0.25 h f(bdry(u1))
    stage_kernel<true, false><<<grid, block, 0, stream>>>(
        zc, u1p, u2p, W1, b1, W2, b2, 0.75f, 0.25f, 0.25f * h);
    // stage 3: z' = bdry(z/3 + 2/3 bdry(u2) + 2h/3 f(bdry(u2)))  (scatter ghosts)
    stage_kernel<true, true><<<grid, block, 0, stream>>>(
        zc, u2p, znext, W1, b1, W2, b2, 1.0f / 3.0f, 2.0f / 3.0f, 2.0f * h / 3.0f);
    zc = znext;
  }
}